// Round 4
// baseline (549.658 us; speedup 1.0000x reference)
//
#include <hip/hip_runtime.h>

// GPConv3D as implicit GEMM on bf16 MFMA.
// out[(o,k)][(b,d,h,w)] = sum_{m,l,v,c,i} ga_sign(i,i^k) W[m,l,v,c,o,i^k] * x[b,c,i,d+m,h+l,w+v] + bias
// M=64 (o*8+k), K=1728 = 27 taps x 64 (c*8+i), N=8*46^3.
// Round-4: v-outer compute restructure. Per (cb,v): load 4 distinct B-row frags x 3 nt
// ONCE (12 ds_read_b128), run all 3 l-taps against them from registers. Kills the 1.5x
// LDS over-read of the l-inner order (rows l+{0,1} overlap across l). B-LDS traffic -33%;
// operand-BW ceiling moves from ~42% to ~55-62% MfmaUtil.
// Kept from round 3: XCD-chunked swizzle, stage-under-compute (now at v==1), setprio
// around MFMA packs, conflict-free [cb][q][col][t8] layout, gload_lds16 staging.

namespace {

constexpr int DIN = 48, DOUT = 46;
constexpr size_t X_ELEMS = 8ull * 8 * 8 * DIN * DIN * DIN;   // 56,623,104
constexpr size_t XBF_BYTES = X_ELEMS * 2;                    // 113,246,208
constexpr int APK_ELEMS = 54 * 4 * 64 * 8;                   // 110,592 bf16
constexpr int ROW_SHORTS = 2 * 4 * 48 * 8;                   // 3072 shorts per (b,z,y) row
constexpr int ROW_BYTES = ROW_SHORTS * 2;                    // 6144 B

__host__ __device__ constexpr int popc_(int v) { int c = 0; while (v) { c += v & 1; v >>= 1; } return c; }
__host__ __device__ inline float ga_sign(int a, int b) {
  int s = 0;
  for (int t = a >> 1; t; t >>= 1) s += popc_(t & b);
  return (s & 1) ? -1.0f : 1.0f;
}

__device__ inline unsigned short f2bf(float f) {  // round-to-nearest-even
  unsigned u = __builtin_bit_cast(unsigned, f);
  u += 0x7fffu + ((u >> 16) & 1u);
  return (unsigned short)(u >> 16);
}

__device__ inline void gload_lds16(const void* g, void* l) {
  __builtin_amdgcn_global_load_lds(
      (const __attribute__((address_space(1))) unsigned int*)g,
      (__attribute__((address_space(3))) unsigned int*)l, 16, 0, 0);
}

using frag  = __attribute__((ext_vector_type(8))) short;  // 8 bf16 (4 VGPRs)
using f32x4 = __attribute__((ext_vector_type(4))) float;

// ---- prep 1: x fp32 -> bf16, transposed to xt[(b*48+z)*48+y][cb][q][x48][t8] ----
// Block = (b, z, y-group of 8). Coalesced float4 reads, LDS [k][y][x] with contiguous
// uint2 writes (conflict-free), gather-transpose reads at stride 384 shorts (conflict-free),
// contiguous uint4 stores.
__global__ __launch_bounds__(256) void cvt_x(const float* __restrict__ x,
                                             unsigned short* __restrict__ xt) {
  const int bid = blockIdx.x;            // (b*48+z)*6 + yg
  const int yg = bid % 6, bz = bid / 6;  // bz = b*48+z
  const int b = bz / 48, z = bz - b * 48;
  const int tid = threadIdx.x;
  __shared__ __attribute__((aligned(16))) unsigned short T[64 * 8 * 48];  // [k][y][x] 49152 B
  const float* src = x + (size_t)b * 64 * 110592 + (size_t)z * 2304 + (size_t)yg * 384;
#pragma unroll
  for (int it = 0; it < 24; ++it) {
    const int i = it * 256 + tid;        // 0..6143 float4s
    const int k = i / 96, j = i - k * 96;
    const int y = j / 12, x4 = j - y * 12;
    float4 f = *(const float4*)(src + (size_t)k * 110592 + y * 48 + x4 * 4);
    uint2 p;
    p.x = (unsigned)f2bf(f.x) | ((unsigned)f2bf(f.y) << 16);
    p.y = (unsigned)f2bf(f.z) | ((unsigned)f2bf(f.w) << 16);
    *(uint2*)&T[(k * 8 + y) * 48 + x4 * 4] = p;
  }
  __syncthreads();
  uint4* dst = (uint4*)(xt + ((size_t)bz * 48 + yg * 8) * ROW_SHORTS);
#pragma unroll
  for (int it = 0; it < 12; ++it) {
    const int C = it * 256 + tid;        // chunk 0..3071 (384 per y-row)
    const int y = C / 384, rem = C - y * 384;
    const int kq = rem / 48, xx = rem - kq * 48;   // kq = cb*4+q
    const unsigned short* p0 = &T[(kq * 64 + y) * 48 + xx];  // + t*384 per t
    const unsigned s0 = p0[0],    s1 = p0[384],  s2 = p0[768],  s3 = p0[1152];
    const unsigned s4 = p0[1536], s5 = p0[1920], s6 = p0[2304], s7 = p0[2688];
    uint4 o;
    o.x = s0 | (s1 << 16); o.y = s2 | (s3 << 16);
    o.z = s4 | (s5 << 16); o.w = s6 | (s7 << 16);
    dst[C] = o;
  }
}

// ---- prep 2: pack A (sign-folded weights) into MFMA fragment order ----
// Apk[e], e = ((s*4+q)*64 + mi)*8 + t ; K-step s = ((m*3+l)*3+v)*2 + cb ; k_local = q*8+t
__global__ __launch_bounds__(256) void build_apk(const float* __restrict__ W,
                                                 unsigned short* __restrict__ Apk) {
  int e = blockIdx.x * 256 + threadIdx.x;  // < 110592
  int t  = e & 7;
  int mi = (e >> 3) & 63;
  int q  = (e >> 9) & 3;
  int s  = e >> 11;                 // 0..53
  int cb = s & 1, mlv = s >> 1;
  int v = mlv % 3, l = (mlv / 3) % 3, m = mlv / 9;
  int kl = cb * 32 + q * 8 + t;     // (c,i)
  int c = kl >> 3, i = kl & 7;
  int o = mi >> 3, kb = mi & 7, j = i ^ kb;
  float val = ga_sign(i, j) * W[((((m * 3 + l) * 3 + v) * 8 + c) * 8 + o) * 8 + j];
  Apk[e] = f2bf(val);
}

// ---- main: implicit GEMM, wave = M64 x (2y x 48w), v-outer register-held B rows ----
__global__ __launch_bounds__(256, 2) void gpconv_mfma(
    const unsigned short* __restrict__ xt,   // [row][cb][q][x48][t8] bf16
    const unsigned short* __restrict__ Apk,  // packed A frags
    const float* __restrict__ bias,          // [64]
    float* __restrict__ out)                 // [8,64,46,46,46]
{
  // XCD-chunked bijective swizzle: 2208 blocks = 8 XCD * 276.
  // Each XCD gets 6 (b,hg)-stripes, d-contiguous -> ~2.9 MB working set per stripe (L2-fit).
  const int fid0 = blockIdx.x + 46 * (blockIdx.y + 6 * blockIdx.z);
  const int fid = (fid0 & 7) * 276 + (fid0 >> 3);
  const int d = fid % 46;
  const int t6 = fid / 46;          // hg + 6*b
  const int hg = t6 % 6, b = t6 / 6;
  const int h0 = hg * 8;
  const int tid = threadIdx.x;
  const int wv = tid >> 6;          // wave id: owns output rows h0 + 2*wv + {0,1}
  const int lane = tid & 63, r = lane & 15, q = lane >> 4;

  // 10 y-rows, each [cb2][q4][col48][t8]; +32 shorts tail pad for col 48/49 over-reads
  // (garbage there feeds only masked outputs w>=46).
  __shared__ __attribute__((aligned(16))) unsigned short Xs[10 * ROW_SHORTS + 32];

  f32x4 acc[4][2][3];
#pragma unroll
  for (int ms = 0; ms < 4; ++ms)
#pragma unroll
    for (int row = 0; row < 2; ++row)
#pragma unroll
      for (int nt = 0; nt < 3; ++nt) acc[ms][row][nt] = (f32x4){0.f, 0.f, 0.f, 0.f};

  const unsigned short* Apl = Apk + q * 512 + r * 8;  // lane-hoisted A base (shorts)

  // stage one cb half-plane (10 rows x 3 KB), 6-9 gloads/wave, linear LDS dest.
  // hg=5 reads rows y=48,49 -> over-read stays inside d_ws (Apk region), outputs masked.
  auto stage_half = [&](int zin, int cb) {
    const size_t R0 = (size_t)(b * 48 + zin) * 48 + h0;
#pragma unroll
    for (int i = 0; i < 3; ++i) {
      const int row = wv + i * 4;
      if (row < 10) {
        const char* g = (const char*)xt + (R0 + row) * ROW_BYTES + cb * 3072 + (size_t)lane * 16;
        unsigned loff = (unsigned)__builtin_amdgcn_readfirstlane(row * ROW_BYTES + cb * 3072);
#pragma unroll
        for (int ip = 0; ip < 3; ++ip)
          gload_lds16(g + ip * 1024, (char*)Xs + loff + ip * 1024);
      }
    }
  };

  // Per (cb, v): read the 4 distinct B rows (x3 nt) once into registers, then run all
  // 3 l-taps against them (B-row index l+row is static after unroll). Staging issued at
  // v==1 (post-barrier epoch of the buffer being overwritten; lands under ~6 MFMA packs).
  auto compute_half = [&](int m, int cb, bool do_stage, int stage_z, int stage_cb) {
    const unsigned short* Xb = Xs + cb * 1536 + q * 384;
    const unsigned short* Ab = Apl + (size_t)m * 9 * 4096 + cb * 2048;
#pragma unroll
    for (int v = 0; v < 3; ++v) {
      frag bfr[4][3];
#pragma unroll
      for (int rw = 0; rw < 4; ++rw) {
        const unsigned short* Xrow = Xb + (wv * 2 + rw) * ROW_SHORTS + (r + v) * 8;
#pragma unroll
        for (int nt = 0; nt < 3; ++nt) bfr[rw][nt] = *(const frag*)(Xrow + nt * 128);
      }
      if (v == 1 && do_stage) stage_half(stage_z, stage_cb);
#pragma unroll
      for (int l = 0; l < 3; ++l) {
        frag a[4];
#pragma unroll
        for (int ms = 0; ms < 4; ++ms)
          a[ms] = *(const frag*)(Ab + (size_t)(l * 3 + v) * 4096 + ms * 128);
        __builtin_amdgcn_s_setprio(1);
#pragma unroll
        for (int ms = 0; ms < 4; ++ms)
#pragma unroll
          for (int row = 0; row < 2; ++row)
#pragma unroll
            for (int nt = 0; nt < 3; ++nt)
              acc[ms][row][nt] = __builtin_amdgcn_mfma_f32_16x16x32_bf16(
                  a[ms], bfr[l + row][nt], acc[ms][row][nt], 0, 0, 0);
        __builtin_amdgcn_s_setprio(0);
      }
    }
  };

  stage_half(d, 0);
  stage_half(d, 1);
  __syncthreads();
#pragma unroll 1
  for (int m = 0; m < 3; ++m) {
    // buf1 <- plane d+m staged inside (for m>=1); needed by compute(m,1) after the sync.
    compute_half(m, 0, m >= 1, d + m, 1);
    __syncthreads();
    // buf0 <- plane d+m+1 staged inside (for m<2); needed by compute(m+1,0) after the sync.
    compute_half(m, 1, m < 2, d + m + 1, 0);
    __syncthreads();
  }

  // epilogue: D[row=q*4+reg][col=r] per 16x16 subtile
#pragma unroll
  for (int row = 0; row < 2; ++row) {
    const int y = h0 + wv * 2 + row;
    if (y < DOUT) {
#pragma unroll
      for (int ms = 0; ms < 4; ++ms) {
#pragma unroll
        for (int nt = 0; nt < 3; ++nt) {
          const int w = nt * 16 + r;
          if (w < DOUT) {
#pragma unroll
            for (int reg = 0; reg < 4; ++reg) {
              const int mrow = ms * 16 + q * 4 + reg;  // o*8+k
              const size_t oidx = (((size_t)(b * 64 + mrow) * DOUT + d) * DOUT + y) * DOUT + w;
              out[oidx] = acc[ms][row][nt][reg] + bias[mrow];
            }
          }
        }
      }
    }
  }
}

}  // namespace

extern "C" void kernel_launch(void* const* d_in, const int* in_sizes, int n_in,
                              void* d_out, int out_size, void* d_ws, size_t ws_size,
                              hipStream_t stream) {
  const float* x    = (const float*)d_in[0];
  const float* W    = (const float*)d_in[1];
  const float* bias = (const float*)d_in[2];
  float* out = (float*)d_out;

  unsigned short* xt  = (unsigned short*)d_ws;
  unsigned short* Apk = (unsigned short*)((char*)d_ws + XBF_BYTES);

  cvt_x<<<8 * 48 * 6, 256, 0, stream>>>(x, xt);            // 2304 blocks
  build_apk<<<APK_ELEMS / 256, 256, 0, stream>>>(W, Apk);  // 432 blocks

  dim3 grid(DOUT, 6, 8);  // (d, h-group of 8, b) = 2208 blocks
  gpconv_mfma<<<grid, 256, 0, stream>>>(xt, Apk, bias, out);
}

// Round 5
// 535.796 us; speedup vs baseline: 1.0259x; 1.0259x over previous
//
#include <hip/hip_runtime.h>

// GPConv3D as implicit GEMM on bf16 MFMA.
// out[(o,k)][(b,d,h,w)] = sum_{m,l,v,c,i} ga_sign(i,i^k) W[m,l,v,c,o,i^k] * x[b,c,i,d+m,h+l,w+v] + bias
// M=64 (o*8+k), K=1728 = 27 taps x 64 (c*8+i), N=8*46^3.
// Round-5: vmcnt de-poisoning. Staging global_load_lds moved to the END of each
// compute-half (same barrier epoch -> same liveness/races as r4, but all of the half's
// A-fragment waits are OLDER than staging in the vmcnt stream, so MFMA packs no longer
// stall behind HBM staging latency). Staging latency is paid once at the barrier drain.
// Re-added a[2] two-slot A-prefetch across the 9 linearized (v,l) steps (functional now
// that the waits are clean). Kept: v-outer B-row hoisting (12 ds_read_b128/round),
// XCD-chunked swizzle, setprio on MFMA packs, conflict-free [cb][q][col][t8] layout.

namespace {

constexpr int DIN = 48, DOUT = 46;
constexpr size_t X_ELEMS = 8ull * 8 * 8 * DIN * DIN * DIN;   // 56,623,104
constexpr size_t XBF_BYTES = X_ELEMS * 2;                    // 113,246,208
constexpr int APK_ELEMS = 54 * 4 * 64 * 8;                   // 110,592 bf16
constexpr int ROW_SHORTS = 2 * 4 * 48 * 8;                   // 3072 shorts per (b,z,y) row
constexpr int ROW_BYTES = ROW_SHORTS * 2;                    // 6144 B

__host__ __device__ constexpr int popc_(int v) { int c = 0; while (v) { c += v & 1; v >>= 1; } return c; }
__host__ __device__ inline float ga_sign(int a, int b) {
  int s = 0;
  for (int t = a >> 1; t; t >>= 1) s += popc_(t & b);
  return (s & 1) ? -1.0f : 1.0f;
}

__device__ inline unsigned short f2bf(float f) {  // round-to-nearest-even
  unsigned u = __builtin_bit_cast(unsigned, f);
  u += 0x7fffu + ((u >> 16) & 1u);
  return (unsigned short)(u >> 16);
}

__device__ inline void gload_lds16(const void* g, void* l) {
  __builtin_amdgcn_global_load_lds(
      (const __attribute__((address_space(1))) unsigned int*)g,
      (__attribute__((address_space(3))) unsigned int*)l, 16, 0, 0);
}

using frag  = __attribute__((ext_vector_type(8))) short;  // 8 bf16 (4 VGPRs)
using f32x4 = __attribute__((ext_vector_type(4))) float;

// ---- prep 1: x fp32 -> bf16, transposed to xt[(b*48+z)*48+y][cb][q][x48][t8] ----
// Block = (b, z, y-group of 8). Coalesced float4 reads, LDS [k][y][x] with contiguous
// uint2 writes (conflict-free), gather-transpose reads at stride 384 shorts (conflict-free),
// contiguous uint4 stores.
__global__ __launch_bounds__(256) void cvt_x(const float* __restrict__ x,
                                             unsigned short* __restrict__ xt) {
  const int bid = blockIdx.x;            // (b*48+z)*6 + yg
  const int yg = bid % 6, bz = bid / 6;  // bz = b*48+z
  const int b = bz / 48, z = bz - b * 48;
  const int tid = threadIdx.x;
  __shared__ __attribute__((aligned(16))) unsigned short T[64 * 8 * 48];  // [k][y][x] 49152 B
  const float* src = x + (size_t)b * 64 * 110592 + (size_t)z * 2304 + (size_t)yg * 384;
#pragma unroll
  for (int it = 0; it < 24; ++it) {
    const int i = it * 256 + tid;        // 0..6143 float4s
    const int k = i / 96, j = i - k * 96;
    const int y = j / 12, x4 = j - y * 12;
    float4 f = *(const float4*)(src + (size_t)k * 110592 + y * 48 + x4 * 4);
    uint2 p;
    p.x = (unsigned)f2bf(f.x) | ((unsigned)f2bf(f.y) << 16);
    p.y = (unsigned)f2bf(f.z) | ((unsigned)f2bf(f.w) << 16);
    *(uint2*)&T[(k * 8 + y) * 48 + x4 * 4] = p;
  }
  __syncthreads();
  uint4* dst = (uint4*)(xt + ((size_t)bz * 48 + yg * 8) * ROW_SHORTS);
#pragma unroll
  for (int it = 0; it < 12; ++it) {
    const int C = it * 256 + tid;        // chunk 0..3071 (384 per y-row)
    const int y = C / 384, rem = C - y * 384;
    const int kq = rem / 48, xx = rem - kq * 48;   // kq = cb*4+q
    const unsigned short* p0 = &T[(kq * 64 + y) * 48 + xx];  // + t*384 per t
    const unsigned s0 = p0[0],    s1 = p0[384],  s2 = p0[768],  s3 = p0[1152];
    const unsigned s4 = p0[1536], s5 = p0[1920], s6 = p0[2304], s7 = p0[2688];
    uint4 o;
    o.x = s0 | (s1 << 16); o.y = s2 | (s3 << 16);
    o.z = s4 | (s5 << 16); o.w = s6 | (s7 << 16);
    dst[C] = o;
  }
}

// ---- prep 2: pack A (sign-folded weights) into MFMA fragment order ----
// Apk[e], e = ((s*4+q)*64 + mi)*8 + t ; K-step s = ((m*3+l)*3+v)*2 + cb ; k_local = q*8+t
__global__ __launch_bounds__(256) void build_apk(const float* __restrict__ W,
                                                 unsigned short* __restrict__ Apk) {
  int e = blockIdx.x * 256 + threadIdx.x;  // < 110592
  int t  = e & 7;
  int mi = (e >> 3) & 63;
  int q  = (e >> 9) & 3;
  int s  = e >> 11;                 // 0..53
  int cb = s & 1, mlv = s >> 1;
  int v = mlv % 3, l = (mlv / 3) % 3, m = mlv / 9;
  int kl = cb * 32 + q * 8 + t;     // (c,i)
  int c = kl >> 3, i = kl & 7;
  int o = mi >> 3, kb = mi & 7, j = i ^ kb;
  float val = ga_sign(i, j) * W[((((m * 3 + l) * 3 + v) * 8 + c) * 8 + o) * 8 + j];
  Apk[e] = f2bf(val);
}

// ---- main: implicit GEMM, wave = M64 x (2y x 48w), end-of-half staging ----
__global__ __launch_bounds__(256, 2) void gpconv_mfma(
    const unsigned short* __restrict__ xt,   // [row][cb][q][x48][t8] bf16
    const unsigned short* __restrict__ Apk,  // packed A frags
    const float* __restrict__ bias,          // [64]
    float* __restrict__ out)                 // [8,64,46,46,46]
{
  // XCD-chunked bijective swizzle: 2208 blocks = 8 XCD * 276.
  // Each XCD gets 6 (b,hg)-stripes, d-contiguous -> ~2.9 MB working set per stripe (L2-fit).
  const int fid0 = blockIdx.x + 46 * (blockIdx.y + 6 * blockIdx.z);
  const int fid = (fid0 & 7) * 276 + (fid0 >> 3);
  const int d = fid % 46;
  const int t6 = fid / 46;          // hg + 6*b
  const int hg = t6 % 6, b = t6 / 6;
  const int h0 = hg * 8;
  const int tid = threadIdx.x;
  const int wv = tid >> 6;          // wave id: owns output rows h0 + 2*wv + {0,1}
  const int lane = tid & 63, r = lane & 15, q = lane >> 4;

  // 10 y-rows, each [cb2][q4][col48][t8]; +32 shorts tail pad for col 48/49 over-reads
  // (garbage there feeds only masked outputs w>=46).
  __shared__ __attribute__((aligned(16))) unsigned short Xs[10 * ROW_SHORTS + 32];

  f32x4 acc[4][2][3];
#pragma unroll
  for (int ms = 0; ms < 4; ++ms)
#pragma unroll
    for (int row = 0; row < 2; ++row)
#pragma unroll
      for (int nt = 0; nt < 3; ++nt) acc[ms][row][nt] = (f32x4){0.f, 0.f, 0.f, 0.f};

  const unsigned short* Apl = Apk + q * 512 + r * 8;  // lane-hoisted A base (shorts)

  // stage one cb half-plane (10 rows x 3 KB), 6-9 gloads/wave, linear LDS dest.
  // hg=5 reads rows y=48,49 -> over-read stays inside d_ws (Apk region), outputs masked.
  auto stage_half = [&](int zin, int cb) {
    const size_t R0 = (size_t)(b * 48 + zin) * 48 + h0;
#pragma unroll
    for (int i = 0; i < 3; ++i) {
      const int row = wv + i * 4;
      if (row < 10) {
        const char* g = (const char*)xt + (R0 + row) * ROW_BYTES + cb * 3072 + (size_t)lane * 16;
        unsigned loff = (unsigned)__builtin_amdgcn_readfirstlane(row * ROW_BYTES + cb * 3072);
#pragma unroll
        for (int ip = 0; ip < 3; ++ip)
          gload_lds16(g + ip * 1024, (char*)Xs + loff + ip * 1024);
      }
    }
  };

  // Pure compute half: 9 linearized (v,l) steps. bfr rows hoisted per v (12 ds_read_b128);
  // A-frags prefetched one step ahead in a 2-slot register pipeline. NO staging inside:
  // all waits here are older than any staging in the vmcnt stream.
  auto compute_half = [&](int m, int cb) {
    const unsigned short* Xb = Xs + cb * 1536 + q * 384;
    const unsigned short* Ab = Apl + (size_t)m * 9 * 4096 + cb * 2048;
    frag a[2][4];
    frag bfr[4][3];
#pragma unroll
    for (int ms = 0; ms < 4; ++ms) a[0][ms] = *(const frag*)(Ab + 0 * 4096 + ms * 128);
#pragma unroll
    for (int s = 0; s < 9; ++s) {
      const int v = s / 3, l = s - v * 3;     // execution order: v-major
      if (l == 0) {
#pragma unroll
        for (int rw = 0; rw < 4; ++rw) {
          const unsigned short* Xrow = Xb + (wv * 2 + rw) * ROW_SHORTS + (r + v) * 8;
#pragma unroll
          for (int nt = 0; nt < 3; ++nt) bfr[rw][nt] = *(const frag*)(Xrow + nt * 128);
        }
      }
      if (s < 8) {
        const int sn = s + 1;
        const int nv = sn / 3, nl = sn - nv * 3;    // next step's (v,l)
#pragma unroll
        for (int ms = 0; ms < 4; ++ms)
          a[sn & 1][ms] = *(const frag*)(Ab + (size_t)(nl * 3 + nv) * 4096 + ms * 128);
      }
      __builtin_amdgcn_s_setprio(1);
#pragma unroll
      for (int ms = 0; ms < 4; ++ms)
#pragma unroll
        for (int row = 0; row < 2; ++row)
#pragma unroll
          for (int nt = 0; nt < 3; ++nt)
            acc[ms][row][nt] = __builtin_amdgcn_mfma_f32_16x16x32_bf16(
                a[s & 1][ms], bfr[l + row][nt], acc[ms][row][nt], 0, 0, 0);
      __builtin_amdgcn_s_setprio(0);
    }
  };

  stage_half(d, 0);
  stage_half(d, 1);
  __syncthreads();
#pragma unroll 1
  for (int m = 0; m < 3; ++m) {
    compute_half(m, 0);
    // buf1 (plane m-1 cb1, dead since last barrier) <- plane d+m cb1; issued AFTER all of
    // this half's A-loads -> no vmcnt poisoning; drained by the barrier below.
    if (m >= 1) stage_half(d + m, 1);
    __syncthreads();
    compute_half(m, 1);
    // buf0 (plane m cb0, consumed above... dead since preceding barrier) <- plane d+m+1 cb0.
    if (m < 2) stage_half(d + m + 1, 0);
    __syncthreads();
  }

  // epilogue: D[row=q*4+reg][col=r] per 16x16 subtile
#pragma unroll
  for (int row = 0; row < 2; ++row) {
    const int y = h0 + wv * 2 + row;
    if (y < DOUT) {
#pragma unroll
      for (int ms = 0; ms < 4; ++ms) {
#pragma unroll
        for (int nt = 0; nt < 3; ++nt) {
          const int w = nt * 16 + r;
          if (w < DOUT) {
#pragma unroll
            for (int reg = 0; reg < 4; ++reg) {
              const int mrow = ms * 16 + q * 4 + reg;  // o*8+k
              const size_t oidx = (((size_t)(b * 64 + mrow) * DOUT + d) * DOUT + y) * DOUT + w;
              out[oidx] = acc[ms][row][nt][reg] + bias[mrow];
            }
          }
        }
      }
    }
  }
}

}  // namespace

extern "C" void kernel_launch(void* const* d_in, const int* in_sizes, int n_in,
                              void* d_out, int out_size, void* d_ws, size_t ws_size,
                              hipStream_t stream) {
  const float* x    = (const float*)d_in[0];
  const float* W    = (const float*)d_in[1];
  const float* bias = (const float*)d_in[2];
  float* out = (float*)d_out;

  unsigned short* xt  = (unsigned short*)d_ws;
  unsigned short* Apk = (unsigned short*)((char*)d_ws + XBF_BYTES);

  cvt_x<<<8 * 48 * 6, 256, 0, stream>>>(x, xt);            // 2304 blocks
  build_apk<<<APK_ELEMS / 256, 256, 0, stream>>>(W, Apk);  // 432 blocks

  dim3 grid(DOUT, 6, 8);  // (d, h-group of 8, b) = 2208 blocks
  gpconv_mfma<<<grid, 256, 0, stream>>>(xt, Apk, bias, out);
}

// Round 6
// 528.880 us; speedup vs baseline: 1.0393x; 1.0131x over previous
//
#include <hip/hip_runtime.h>

// GPConv3D as implicit GEMM on bf16 MFMA.
// out[(o,k)][(b,d,h,w)] = sum_{m,l,v,c,i} ga_sign(i,i^k) W[m,l,v,c,o,i^k] * x[b,c,i,d+m,h+l,w+v] + bias
// M=64 (o*8+k), K=1728 = 27 taps x 64 (c*8+i), N=8*46^3.
// Round-6:
//  - bfr v-level DOUBLE-BUFFER: v+1's 12 ds_read_b128 issued under v's 3 MFMA packs,
//    removing the lgkmcnt stall at every v boundary (18x per block). +48 VGPR (~244
//    unified, fits 2 waves/SIMD).
//  - prep kernels merged into one launch (block-range dispatch).
// Kept from r5: end-of-half staging (vmcnt-clean), a[2] A-prefetch, v-outer B-row hoist,
// XCD-chunked swizzle, setprio on packs, conflict-free [cb][q][col][t8] layout.

namespace {

constexpr int DIN = 48, DOUT = 46;
constexpr size_t X_ELEMS = 8ull * 8 * 8 * DIN * DIN * DIN;   // 56,623,104
constexpr size_t XBF_BYTES = X_ELEMS * 2;                    // 113,246,208
constexpr int APK_ELEMS = 54 * 4 * 64 * 8;                   // 110,592 bf16
constexpr int ROW_SHORTS = 2 * 4 * 48 * 8;                   // 3072 shorts per (b,z,y) row
constexpr int ROW_BYTES = ROW_SHORTS * 2;                    // 6144 B
constexpr int CVT_BLOCKS = 8 * 48 * 6;                       // 2304
constexpr int APK_BLOCKS = APK_ELEMS / 256;                  // 432

__host__ __device__ constexpr int popc_(int v) { int c = 0; while (v) { c += v & 1; v >>= 1; } return c; }
__host__ __device__ inline float ga_sign(int a, int b) {
  int s = 0;
  for (int t = a >> 1; t; t >>= 1) s += popc_(t & b);
  return (s & 1) ? -1.0f : 1.0f;
}

__device__ inline unsigned short f2bf(float f) {  // round-to-nearest-even
  unsigned u = __builtin_bit_cast(unsigned, f);
  u += 0x7fffu + ((u >> 16) & 1u);
  return (unsigned short)(u >> 16);
}

__device__ inline void gload_lds16(const void* g, void* l) {
  __builtin_amdgcn_global_load_lds(
      (const __attribute__((address_space(1))) unsigned int*)g,
      (__attribute__((address_space(3))) unsigned int*)l, 16, 0, 0);
}

using frag  = __attribute__((ext_vector_type(8))) short;  // 8 bf16 (4 VGPRs)
using f32x4 = __attribute__((ext_vector_type(4))) float;

// ---- prep (merged): blocks [0,2304) transpose x; blocks [2304,2736) pack A ----
__global__ __launch_bounds__(256) void prep(const float* __restrict__ x,
                                            const float* __restrict__ W,
                                            unsigned short* __restrict__ xt,
                                            unsigned short* __restrict__ Apk) {
  const int tid = threadIdx.x;
  if (blockIdx.x >= CVT_BLOCKS) {
    // pack A (sign-folded weights) into MFMA fragment order.
    // Apk[e], e = ((s*4+q)*64 + mi)*8 + t ; K-step s = ((m*3+l)*3+v)*2 + cb
    int e = (blockIdx.x - CVT_BLOCKS) * 256 + tid;  // < 110592
    int t  = e & 7;
    int mi = (e >> 3) & 63;
    int q  = (e >> 9) & 3;
    int s  = e >> 11;                 // 0..53
    int cb = s & 1, mlv = s >> 1;
    int v = mlv % 3, l = (mlv / 3) % 3, m = mlv / 9;
    int kl = cb * 32 + q * 8 + t;     // (c,i)
    int c = kl >> 3, i = kl & 7;
    int o = mi >> 3, kb = mi & 7, j = i ^ kb;
    float val = ga_sign(i, j) * W[((((m * 3 + l) * 3 + v) * 8 + c) * 8 + o) * 8 + j];
    Apk[e] = f2bf(val);
    return;
  }
  // x fp32 -> bf16, transposed to xt[(b*48+z)*48+y][cb][q][x48][t8].
  // Block = (b, z, y-group of 8). Coalesced float4 reads, LDS [k][y][x] with contiguous
  // uint2 writes (conflict-free), stride-384 u16 gather reads (conflict-free),
  // contiguous uint4 stores.
  const int bid = blockIdx.x;            // (b*48+z)*6 + yg
  const int yg = bid % 6, bz = bid / 6;  // bz = b*48+z
  const int b = bz / 48, z = bz - b * 48;
  __shared__ __attribute__((aligned(16))) unsigned short T[64 * 8 * 48];  // [k][y][x] 49152 B
  const float* src = x + (size_t)b * 64 * 110592 + (size_t)z * 2304 + (size_t)yg * 384;
#pragma unroll
  for (int it = 0; it < 24; ++it) {
    const int i = it * 256 + tid;        // 0..6143 float4s
    const int k = i / 96, j = i - k * 96;
    const int y = j / 12, x4 = j - y * 12;
    float4 f = *(const float4*)(src + (size_t)k * 110592 + y * 48 + x4 * 4);
    uint2 p;
    p.x = (unsigned)f2bf(f.x) | ((unsigned)f2bf(f.y) << 16);
    p.y = (unsigned)f2bf(f.z) | ((unsigned)f2bf(f.w) << 16);
    *(uint2*)&T[(k * 8 + y) * 48 + x4 * 4] = p;
  }
  __syncthreads();
  uint4* dst = (uint4*)(xt + ((size_t)bz * 48 + yg * 8) * ROW_SHORTS);
#pragma unroll
  for (int it = 0; it < 12; ++it) {
    const int C = it * 256 + tid;        // chunk 0..3071 (384 per y-row)
    const int y = C / 384, rem = C - y * 384;
    const int kq = rem / 48, xx = rem - kq * 48;   // kq = cb*4+q
    const unsigned short* p0 = &T[(kq * 64 + y) * 48 + xx];  // + t*384 per t
    const unsigned s0 = p0[0],    s1 = p0[384],  s2 = p0[768],  s3 = p0[1152];
    const unsigned s4 = p0[1536], s5 = p0[1920], s6 = p0[2304], s7 = p0[2688];
    uint4 o;
    o.x = s0 | (s1 << 16); o.y = s2 | (s3 << 16);
    o.z = s4 | (s5 << 16); o.w = s6 | (s7 << 16);
    dst[C] = o;
  }
}

// ---- main: implicit GEMM, wave = M64 x (2y x 48w), bfr v-dbuf + end-of-half staging ----
__global__ __launch_bounds__(256, 2) void gpconv_mfma(
    const unsigned short* __restrict__ xt,   // [row][cb][q][x48][t8] bf16
    const unsigned short* __restrict__ Apk,  // packed A frags
    const float* __restrict__ bias,          // [64]
    float* __restrict__ out)                 // [8,64,46,46,46]
{
  // XCD-chunked bijective swizzle: 2208 blocks = 8 XCD * 276.
  const int fid0 = blockIdx.x + 46 * (blockIdx.y + 6 * blockIdx.z);
  const int fid = (fid0 & 7) * 276 + (fid0 >> 3);
  const int d = fid % 46;
  const int t6 = fid / 46;          // hg + 6*b
  const int hg = t6 % 6, b = t6 / 6;
  const int h0 = hg * 8;
  const int tid = threadIdx.x;
  const int wv = tid >> 6;          // wave id: owns output rows h0 + 2*wv + {0,1}
  const int lane = tid & 63, r = lane & 15, q = lane >> 4;

  // 10 y-rows, each [cb2][q4][col48][t8]; +32 shorts tail pad for col 48/49 over-reads
  // (garbage there feeds only masked outputs w>=46).
  __shared__ __attribute__((aligned(16))) unsigned short Xs[10 * ROW_SHORTS + 32];

  f32x4 acc[4][2][3];
#pragma unroll
  for (int ms = 0; ms < 4; ++ms)
#pragma unroll
    for (int row = 0; row < 2; ++row)
#pragma unroll
      for (int nt = 0; nt < 3; ++nt) acc[ms][row][nt] = (f32x4){0.f, 0.f, 0.f, 0.f};

  const unsigned short* Apl = Apk + q * 512 + r * 8;  // lane-hoisted A base (shorts)

  // stage one cb half-plane (10 rows x 3 KB), 6-9 gloads/wave, linear LDS dest.
  // hg=5 reads rows y=48,49 -> over-read stays inside d_ws (Apk region), outputs masked.
  auto stage_half = [&](int zin, int cb) {
    const size_t R0 = (size_t)(b * 48 + zin) * 48 + h0;
#pragma unroll
    for (int i = 0; i < 3; ++i) {
      const int row = wv + i * 4;
      if (row < 10) {
        const char* g = (const char*)xt + (R0 + row) * ROW_BYTES + cb * 3072 + (size_t)lane * 16;
        unsigned loff = (unsigned)__builtin_amdgcn_readfirstlane(row * ROW_BYTES + cb * 3072);
#pragma unroll
        for (int ip = 0; ip < 3; ++ip)
          gload_lds16(g + ip * 1024, (char*)Xs + loff + ip * 1024);
      }
    }
  };

  // Pure compute half: 9 steps (v-major). bfr double-buffered at v granularity:
  // v+1's 12 ds_read_b128 issued under v's 3 MFMA packs. A-frags prefetched one step
  // ahead (2-slot). NO staging inside (vmcnt stream stays clean for A-waits).
  auto compute_half = [&](int m, int cb) {
    const unsigned short* Xb = Xs + cb * 1536 + q * 384;
    const unsigned short* Ab = Apl + (size_t)m * 9 * 4096 + cb * 2048;
    frag a[2][4];
    frag bfr[2][4][3];                        // [v&1][row][nt]
#pragma unroll
    for (int ms = 0; ms < 4; ++ms) a[0][ms] = *(const frag*)(Ab + 0 * 4096 + ms * 128);
#pragma unroll
    for (int rw = 0; rw < 4; ++rw) {          // preload v=0 rows
      const unsigned short* Xrow = Xb + (wv * 2 + rw) * ROW_SHORTS + r * 8;
#pragma unroll
      for (int nt = 0; nt < 3; ++nt) bfr[0][rw][nt] = *(const frag*)(Xrow + nt * 128);
    }
#pragma unroll
    for (int s = 0; s < 9; ++s) {
      const int v = s / 3, l = s - v * 3;     // compile-time after unroll
      if (l == 0 && v < 2) {                  // issue v+1's rows under this v's 3 packs
#pragma unroll
        for (int rw = 0; rw < 4; ++rw) {
          const unsigned short* Xrow = Xb + (wv * 2 + rw) * ROW_SHORTS + (r + v + 1) * 8;
#pragma unroll
          for (int nt = 0; nt < 3; ++nt)
            bfr[(v + 1) & 1][rw][nt] = *(const frag*)(Xrow + nt * 128);
        }
      }
      if (s < 8) {
        const int sn = s + 1;
        const int nv = sn / 3, nl = sn - nv * 3;
#pragma unroll
        for (int ms = 0; ms < 4; ++ms)
          a[sn & 1][ms] = *(const frag*)(Ab + (size_t)(nl * 3 + nv) * 4096 + ms * 128);
      }
      __builtin_amdgcn_s_setprio(1);
#pragma unroll
      for (int ms = 0; ms < 4; ++ms)
#pragma unroll
        for (int row = 0; row < 2; ++row)
#pragma unroll
          for (int nt = 0; nt < 3; ++nt)
            acc[ms][row][nt] = __builtin_amdgcn_mfma_f32_16x16x32_bf16(
                a[s & 1][ms], bfr[v & 1][l + row][nt], acc[ms][row][nt], 0, 0, 0);
      __builtin_amdgcn_s_setprio(0);
    }
  };

  stage_half(d, 0);
  stage_half(d, 1);
  __syncthreads();
#pragma unroll 1
  for (int m = 0; m < 3; ++m) {
    compute_half(m, 0);
    // buf1 (dead since last barrier) <- plane d+m cb1; issued AFTER this half's A-loads
    // -> no vmcnt poisoning; drained by the barrier below.
    if (m >= 1) stage_half(d + m, 1);
    __syncthreads();
    compute_half(m, 1);
    if (m < 2) stage_half(d + m + 1, 0);
    __syncthreads();
  }

  // epilogue: D[row=q*4+reg][col=r] per 16x16 subtile
#pragma unroll
  for (int row = 0; row < 2; ++row) {
    const int y = h0 + wv * 2 + row;
    if (y < DOUT) {
#pragma unroll
      for (int ms = 0; ms < 4; ++ms) {
#pragma unroll
        for (int nt = 0; nt < 3; ++nt) {
          const int w = nt * 16 + r;
          if (w < DOUT) {
#pragma unroll
            for (int reg = 0; reg < 4; ++reg) {
              const int mrow = ms * 16 + q * 4 + reg;  // o*8+k
              const size_t oidx = (((size_t)(b * 64 + mrow) * DOUT + d) * DOUT + y) * DOUT + w;
              out[oidx] = acc[ms][row][nt][reg] + bias[mrow];
            }
          }
        }
      }
    }
  }
}

}  // namespace

extern "C" void kernel_launch(void* const* d_in, const int* in_sizes, int n_in,
                              void* d_out, int out_size, void* d_ws, size_t ws_size,
                              hipStream_t stream) {
  const float* x    = (const float*)d_in[0];
  const float* W    = (const float*)d_in[1];
  const float* bias = (const float*)d_in[2];
  float* out = (float*)d_out;

  unsigned short* xt  = (unsigned short*)d_ws;
  unsigned short* Apk = (unsigned short*)((char*)d_ws + XBF_BYTES);

  prep<<<CVT_BLOCKS + APK_BLOCKS, 256, 0, stream>>>(x, W, xt, Apk);  // 2736 blocks

  dim3 grid(DOUT, 6, 8);  // (d, h-group of 8, b) = 2208 blocks
  gpconv_mfma<<<grid, 256, 0, stream>>>(xt, Apk, bias, out);
}